// Round 16
// baseline (5323.728 us; speedup 1.0000x reference)
//
#include <hip/hip_runtime.h>
#include <math.h>

// QPLayer: batched primal-dual IPM, Q=0, G=-I (LP). f64 inputs DELIVERED AS F32
// (established round 8). Schur complement S = A diag(s/z) A^T (40x40), solved
// with COMPLETE-DIAGONAL-PIVOTED LDL^T (greedy max pivot; load-bearing), lane i
// owns row i of S in registers.
// ROUND 16: same math as r15, cheap cross-lane machinery. r15 was 80% stall at
// 1 wave/SIMD: __shfl == ds_bpermute/ds_swizzle (LDS pipe, ~100cyc dependent)
// for every broadcast/butterfly. Now: uniform-lane broadcasts = v_readlane
// pairs (VALU); argmax = packed u32 key (hi32-of-f64, sign-fixed | lane) via
// 6-step DPP max; mu/alpha/ssum reductions = DPP f64 sum/min; pivot-column
// fetch = depth-6 static select tree; P4 prefetches Lm into dead Sreg regs.
// 3 barriers/iter. One wave per batch element; 1024 waves = 4/CU (structural).

#define NXV   64
#define MEQ   40
#define NITER 25
#define SIGMA_C 0.1
#define FTB_C   0.99
#define SA 65    // LDS row stride for A (doubles)
#define SS 41    // LDS row stride for S staging (doubles); Sl reused for Lm
#define PIV_DROP_REL 1e-12

union DU { double d; int i[2]; unsigned u[2]; };

__device__ __forceinline__ double readlane_f64(double v, int lane) {
    DU a; a.d = v; DU r;
    r.i[0] = __builtin_amdgcn_readlane(a.i[0], lane);
    r.i[1] = __builtin_amdgcn_readlane(a.i[1], lane);
    return r.d;
}

// DPP wave64 reduction ladder: row_shr 1,2,4,8 then row_bcast15, row_bcast31;
// total lands in lane 63. Invalid-source lanes contribute the identity.
template<int CTRL>
__device__ __forceinline__ double dpp_add_step(double v) {
    DU a; a.d = v; DU b;
    b.i[0] = __builtin_amdgcn_update_dpp(0, a.i[0], CTRL, 0xf, 0xf, true);
    b.i[1] = __builtin_amdgcn_update_dpp(0, a.i[1], CTRL, 0xf, 0xf, true);
    return v + b.d;
}
__device__ __forceinline__ double wave_sum_f64(double v) {
    v = dpp_add_step<0x111>(v); v = dpp_add_step<0x112>(v);
    v = dpp_add_step<0x114>(v); v = dpp_add_step<0x118>(v);
    v = dpp_add_step<0x142>(v); v = dpp_add_step<0x143>(v);
    return readlane_f64(v, 63);
}
template<int CTRL>
__device__ __forceinline__ double dpp_min_step(double v) {   // identity +inf
    DU a; a.d = v; DU b;
    b.i[0] = __builtin_amdgcn_update_dpp(0x00000000, a.i[0], CTRL, 0xf, 0xf, false);
    b.i[1] = __builtin_amdgcn_update_dpp(0x7ff00000, a.i[1], CTRL, 0xf, 0xf, false);
    return fmin(v, b.d);
}
__device__ __forceinline__ double wave_min_f64(double v) {
    v = dpp_min_step<0x111>(v); v = dpp_min_step<0x112>(v);
    v = dpp_min_step<0x114>(v); v = dpp_min_step<0x118>(v);
    v = dpp_min_step<0x142>(v); v = dpp_min_step<0x143>(v);
    return readlane_f64(v, 63);
}
template<int CTRL>
__device__ __forceinline__ double dpp_max_step(double v) {   // identity -inf
    DU a; a.d = v; DU b;
    b.i[0] = __builtin_amdgcn_update_dpp(0x00000000, a.i[0], CTRL, 0xf, 0xf, false);
    b.i[1] = __builtin_amdgcn_update_dpp((int)0xfff00000u, a.i[1], CTRL, 0xf, 0xf, false);
    return fmax(v, b.d);
}
__device__ __forceinline__ double wave_max_f64(double v) {
    v = dpp_max_step<0x111>(v); v = dpp_max_step<0x112>(v);
    v = dpp_max_step<0x114>(v); v = dpp_max_step<0x118>(v);
    v = dpp_max_step<0x142>(v); v = dpp_max_step<0x143>(v);
    return readlane_f64(v, 63);
}
template<int CTRL>
__device__ __forceinline__ unsigned dpp_maxu_step(unsigned v) {
    unsigned m = (unsigned)__builtin_amdgcn_update_dpp(0, (int)v, CTRL, 0xf, 0xf, true);
    return v > m ? v : m;
}
__device__ __forceinline__ unsigned wave_max_u32(unsigned v) {
    v = dpp_maxu_step<0x111>(v); v = dpp_maxu_step<0x112>(v);
    v = dpp_maxu_step<0x114>(v); v = dpp_maxu_step<0x118>(v);
    v = dpp_maxu_step<0x142>(v); v = dpp_maxu_step<0x143>(v);
    return (unsigned)__builtin_amdgcn_readlane((int)v, 63);
}

__global__ __launch_bounds__(64, 1)
void qp_ipm_kernel(const float* __restrict__ puzzles,
                   const float* __restrict__ Af,
                   const float* __restrict__ lzf,
                   const float* __restrict__ uf,
                   float* __restrict__ out)
{
    __shared__ double Ald[MEQ * SA];   // 20,800 B
    __shared__ double Sl[MEQ * SS];    // 13,120 B (S staging, then Lm store)
    __shared__ double dl[NXV];         //    512 B

    const int tid = threadIdx.x;       // 0..63, one wave
    const int b   = blockIdx.x;
    const int row = (tid < MEQ) ? tid : 0;

    for (int e = tid; e < MEQ * NXV; e += 64)
        Ald[(e >> 6) * SA + (e & 63)] = (double)Af[e];
    const double ez = exp((double)lzf[tid]);
    __syncthreads();
    double b_r = 0.0;
    #pragma unroll
    for (int i = 0; i < NXV; ++i) b_r += Ald[row * SA + i] * readlane_f64(ez, i);

    const double u_i = (double)uf[tid];
    const double p_i = -(double)puzzles[b * NXV + tid];
    double x_r = 0.0, s_r = 1.0, z_r = 1.0, y_r = 0.0;

    for (int it = 0; it < NITER; ++it) {
        // ---- P1: residuals/scalings ----
        double aty = 0.0;
        #pragma unroll
        for (int j = 0; j < MEQ; ++j) aty += Ald[j * SA + tid] * readlane_f64(y_r, j);
        const double rd = p_i + aty - z_r;          // Q=0, G^T z = -z
        const double rs = s_r - x_r - u_i;          // -x + s - u
        const double mu = wave_sum_f64(s_r * z_r) * (1.0 / 64.0);
        const double rc = (SIGMA_C * mu - z_r * s_r + z_r * rs) / s_r;
        const double rx = rc - rd;                  // rhs_x
        const double d_r = s_r / z_r;
        const double v_r = d_r * rx + x_r;          // fy = A v - b

        double fy_r = 0.0;
        #pragma unroll
        for (int i = 0; i < NXV; ++i) fy_r += Ald[row * SA + i] * readlane_f64(v_r, i);
        fy_r -= b_r;

        dl[tid] = d_r;
        __syncthreads();                            // barrier 0: dl visible

        // ---- P2: S = A diag(d) A^T, 4x4 lower tiles (lanes<55) -> LDS ----
        if (tid < 55) {
            int uu = tid, mb = 0;
            while (uu > mb) { uu -= (mb + 1); ++mb; }
            const int nb = uu;
            double a00=0,a01=0,a02=0,a03=0, a10=0,a11=0,a12=0,a13=0,
                   a20=0,a21=0,a22=0,a23=0, a30=0,a31=0,a32=0,a33=0;
            const double* Am = &Ald[(4 * mb) * SA];
            const double* An = &Ald[(4 * nb) * SA];
            for (int k = 0; k < NXV; ++k) {
                const double dk = dl[k];
                const double r0 = Am[0*SA+k], r1 = Am[1*SA+k], r2 = Am[2*SA+k], r3 = Am[3*SA+k];
                const double c0 = An[0*SA+k]*dk, c1 = An[1*SA+k]*dk, c2 = An[2*SA+k]*dk, c3 = An[3*SA+k]*dk;
                a00 += r0*c0; a01 += r0*c1; a02 += r0*c2; a03 += r0*c3;
                a10 += r1*c0; a11 += r1*c1; a12 += r1*c2; a13 += r1*c3;
                a20 += r2*c0; a21 += r2*c1; a22 += r2*c2; a23 += r2*c3;
                a30 += r3*c0; a31 += r3*c1; a32 += r3*c2; a33 += r3*c3;
            }
            double* Sp = &Sl[(4 * mb) * SS + 4 * nb];
            Sp[0*SS+0]=a00; Sp[0*SS+1]=a01; Sp[0*SS+2]=a02; Sp[0*SS+3]=a03;
            Sp[1*SS+0]=a10; Sp[1*SS+1]=a11; Sp[1*SS+2]=a12; Sp[1*SS+3]=a13;
            Sp[2*SS+0]=a20; Sp[2*SS+1]=a21; Sp[2*SS+2]=a22; Sp[2*SS+3]=a23;
            Sp[3*SS+0]=a30; Sp[3*SS+1]=a31; Sp[3*SS+2]=a32; Sp[3*SS+3]=a33;
        }
        __syncthreads();   // barrier 1: tiles visible

        // ---- load row tid of S into registers (symmetric fill) ----
        double Sreg[MEQ];
        double diag_r;
        if (tid < MEQ) {
            #pragma unroll
            for (int j = 0; j < MEQ; ++j)
                Sreg[j] = (j <= tid) ? Sl[tid * SS + j] : Sl[j * SS + tid];
            diag_r = Sl[tid * SS + tid];
        } else {
            #pragma unroll
            for (int j = 0; j < MEQ; ++j) Sreg[j] = 0.0;
            diag_r = -1.0e308;
        }
        const double dg  = wave_max_f64(diag_r);
        const double thr = dg * PIV_DROP_REL;
        __syncthreads();   // barrier 2: Sl dead -> reuse as Lm store

        // ---- P3: greedy-max-pivot LDL^T; broadcasts via v_readlane ----
        double ip_own = 0.0;
        int    kk_own = 0;
        for (int t = 0; t < MEQ; ++t) {
            // packed-key argmax: sign-fixed hi32 | lane, DPP u32 max
            DU dd; dd.d = diag_r;
            const unsigned h  = dd.u[1];
            const unsigned mk = (h & 0x80000000u) ? ~h : (h | 0x80000000u);
            const unsigned key = wave_max_u32((mk & 0xFFFFFFC0u) | (unsigned)tid);
            const int kt = (int)(key & 63u);
            // col_i = S[i][kt] — depth-6 static select tree
            double ta[20];
            #pragma unroll
            for (int q = 0; q < 20; ++q) ta[q] = (kt & 1) ? Sreg[2*q+1] : Sreg[2*q];
            double tb[10];
            #pragma unroll
            for (int q = 0; q < 10; ++q) tb[q] = (kt & 2) ? ta[2*q+1] : ta[2*q];
            double tc[5];
            #pragma unroll
            for (int q = 0; q < 5; ++q) tc[q] = (kt & 4) ? tb[2*q+1] : tb[2*q];
            const double td0 = (kt & 8)  ? tc[1] : tc[0];
            const double td1 = (kt & 8)  ? tc[3] : tc[2];
            const double te  = (kt & 16) ? td1 : td0;
            const double col = (kt & 32) ? tc[4] : te;

            const double piv  = readlane_f64(col, kt);
            double invP = 1.0 / piv;
            invP = (piv > thr) ? invP : 0.0;        // drop noise pivots
            if (tid == t) { kk_own = kt; ip_own = invP; }
            const double Lm = (diag_r > -1.0e307 && tid != kt) ? col * invP : 0.0;
            if (tid < MEQ) Sl[t * MEQ + tid] = Lm;  // multiplier -> dead LDS
            const double fyk = readlane_f64(fy_r, kt);
            fy_r -= Lm * fyk;                       // unit-L forward solve
            #pragma unroll
            for (int j = 0; j < MEQ; ++j)           // rank-1 trailing update
                Sreg[j] -= Lm * readlane_f64(Sreg[j], kt);
            diag_r -= Lm * col;                     // selector maintenance
            if (tid == kt) diag_r = -1.0e308;       // eliminated
        }

        // ---- P4: backward solve; Lm prefetched into dead Sreg registers ----
        #pragma unroll
        for (int t = 0; t < MEQ; ++t)
            Sreg[t] = (tid < MEQ) ? Sl[t * MEQ + tid] : 0.0;
        double X_r = 0.0;
        #pragma unroll
        for (int t = MEQ - 1; t >= 0; --t) {
            const double ssum = wave_sum_f64(Sreg[t] * X_r);
            const int    kt2  = __builtin_amdgcn_readlane(kk_own, t);
            const double ipt  = readlane_f64(ip_own, t);
            const double fyk  = readlane_f64(fy_r, kt2);
            double xt = fyk * ipt - ssum;
            xt = (ipt != 0.0) ? xt : 0.0;           // dropped direction -> 0
            X_r = (tid == kt2) ? xt : X_r;
        }

        // ---- P5: dx/ds/dz, ratio test (DPP min), updates ----
        double atdy = 0.0;
        #pragma unroll
        for (int j = 0; j < MEQ; ++j) atdy += Ald[j * SA + tid] * readlane_f64(X_r, j);
        const double dx = d_r * (rx - atdy);
        const double ds = dx - rs;                   // -rs + dx
        const double dz = rc - (z_r / s_r) * dx;
        double r = 1.0e300;
        if (ds < 0.0) r = -s_r / ds;
        if (dz < 0.0) r = fmin(r, -z_r / dz);
        r = wave_min_f64(r);
        const double alpha = fmin(1.0, FTB_C * r);
        x_r += alpha * dx;
        s_r += alpha * ds;
        z_r += alpha * dz;
        y_r += alpha * X_r;                          // X_r==0 for lanes>=40
        __syncthreads();                             // Sl(Lm) dead before next P2
    }

    out[b * NXV + tid] = (float)x_r;
}

extern "C" void kernel_launch(void* const* d_in, const int* in_sizes, int n_in,
                              void* d_out, int out_size, void* d_ws, size_t ws_size,
                              hipStream_t stream) {
    const float* puzzles = (const float*)d_in[0];
    const float* A       = (const float*)d_in[1];   // declared f64, delivered f32
    const float* logz0   = (const float*)d_in[2];
    // d_in[3] = Q (zeros, structural), d_in[4] = G (-I, structural)
    const float* u       = (const float*)d_in[5];
    float* out = (float*)d_out;

    const int n_batch = in_sizes[0] / NXV;   // 1024
    qp_ipm_kernel<<<n_batch, 64, 0, stream>>>(puzzles, A, logz0, u, out);
}

// Round 17
// 1810.904 us; speedup vs baseline: 2.9398x; 2.9398x over previous
//
#include <hip/hip_runtime.h>
#include <math.h>

// QPLayer: batched primal-dual IPM, Q=0, G=-I (LP). f64 inputs DELIVERED AS F32
// (established round 8). Schur complement S = A diag(s/z) A^T (40x40), solved
// with COMPLETE-DIAGONAL-PIVOTED LDL^T (greedy max pivot; load-bearing), lane i
// owns row i of S in registers.
// ROUND 17 = r15 structure + r16's verified DPP/readlane machinery, MINUS the
// register-hungry select tree that spilled Sreg to scratch (r16: 31 GB/dispatch
// scratch traffic, HBM 70% peak, 5.3 ms). Pivot-column fetch = 4 independent
// depth-10 cndmask chains + 3 combines (4 temp doubles only). Lm multipliers
// live in the dead Sl LDS buffer (r15 scheme). 3 barriers/iter. One wave per
// batch element; 1024 waves = 4/CU (structural).

#define NXV   64
#define MEQ   40
#define NITER 25
#define SIGMA_C 0.1
#define FTB_C   0.99
#define SA 65    // LDS row stride for A (doubles)
#define SS 41    // LDS row stride for S staging (doubles); Sl reused for Lm
#define PIV_DROP_REL 1e-12

union DU { double d; int i[2]; unsigned u[2]; };

__device__ __forceinline__ double readlane_f64(double v, int lane) {
    DU a; a.d = v; DU r;
    r.i[0] = __builtin_amdgcn_readlane(a.i[0], lane);
    r.i[1] = __builtin_amdgcn_readlane(a.i[1], lane);
    return r.d;
}

// DPP wave64 reduction ladders (verified bit-exact in round 16).
template<int CTRL>
__device__ __forceinline__ double dpp_add_step(double v) {
    DU a; a.d = v; DU b;
    b.i[0] = __builtin_amdgcn_update_dpp(0, a.i[0], CTRL, 0xf, 0xf, true);
    b.i[1] = __builtin_amdgcn_update_dpp(0, a.i[1], CTRL, 0xf, 0xf, true);
    return v + b.d;
}
__device__ __forceinline__ double wave_sum_f64(double v) {
    v = dpp_add_step<0x111>(v); v = dpp_add_step<0x112>(v);
    v = dpp_add_step<0x114>(v); v = dpp_add_step<0x118>(v);
    v = dpp_add_step<0x142>(v); v = dpp_add_step<0x143>(v);
    return readlane_f64(v, 63);
}
template<int CTRL>
__device__ __forceinline__ double dpp_min_step(double v) {   // identity +inf
    DU a; a.d = v; DU b;
    b.i[0] = __builtin_amdgcn_update_dpp(0x00000000, a.i[0], CTRL, 0xf, 0xf, false);
    b.i[1] = __builtin_amdgcn_update_dpp(0x7ff00000, a.i[1], CTRL, 0xf, 0xf, false);
    return fmin(v, b.d);
}
__device__ __forceinline__ double wave_min_f64(double v) {
    v = dpp_min_step<0x111>(v); v = dpp_min_step<0x112>(v);
    v = dpp_min_step<0x114>(v); v = dpp_min_step<0x118>(v);
    v = dpp_min_step<0x142>(v); v = dpp_min_step<0x143>(v);
    return readlane_f64(v, 63);
}
template<int CTRL>
__device__ __forceinline__ double dpp_max_step(double v) {   // identity -inf
    DU a; a.d = v; DU b;
    b.i[0] = __builtin_amdgcn_update_dpp(0x00000000, a.i[0], CTRL, 0xf, 0xf, false);
    b.i[1] = __builtin_amdgcn_update_dpp((int)0xfff00000u, a.i[1], CTRL, 0xf, 0xf, false);
    return fmax(v, b.d);
}
__device__ __forceinline__ double wave_max_f64(double v) {
    v = dpp_max_step<0x111>(v); v = dpp_max_step<0x112>(v);
    v = dpp_max_step<0x114>(v); v = dpp_max_step<0x118>(v);
    v = dpp_max_step<0x142>(v); v = dpp_max_step<0x143>(v);
    return readlane_f64(v, 63);
}
template<int CTRL>
__device__ __forceinline__ unsigned dpp_maxu_step(unsigned v) {
    unsigned m = (unsigned)__builtin_amdgcn_update_dpp(0, (int)v, CTRL, 0xf, 0xf, true);
    return v > m ? v : m;
}
__device__ __forceinline__ unsigned wave_max_u32(unsigned v) {
    v = dpp_maxu_step<0x111>(v); v = dpp_maxu_step<0x112>(v);
    v = dpp_maxu_step<0x114>(v); v = dpp_maxu_step<0x118>(v);
    v = dpp_maxu_step<0x142>(v); v = dpp_maxu_step<0x143>(v);
    return (unsigned)__builtin_amdgcn_readlane((int)v, 63);
}

__global__ __launch_bounds__(64, 1)
void qp_ipm_kernel(const float* __restrict__ puzzles,
                   const float* __restrict__ Af,
                   const float* __restrict__ lzf,
                   const float* __restrict__ uf,
                   float* __restrict__ out)
{
    __shared__ double Ald[MEQ * SA];   // 20,800 B
    __shared__ double Sl[MEQ * SS];    // 13,120 B (S staging, then Lm store)
    __shared__ double dl[NXV];         //    512 B

    const int tid = threadIdx.x;       // 0..63, one wave
    const int b   = blockIdx.x;
    const int row = (tid < MEQ) ? tid : 0;

    for (int e = tid; e < MEQ * NXV; e += 64)
        Ald[(e >> 6) * SA + (e & 63)] = (double)Af[e];
    const double ez = exp((double)lzf[tid]);
    __syncthreads();
    double b_r = 0.0;
    #pragma unroll 4
    for (int i = 0; i < NXV; ++i) b_r += Ald[row * SA + i] * readlane_f64(ez, i);

    const double u_i = (double)uf[tid];
    const double p_i = -(double)puzzles[b * NXV + tid];
    double x_r = 0.0, s_r = 1.0, z_r = 1.0, y_r = 0.0;

    for (int it = 0; it < NITER; ++it) {
        // ---- P1: residuals/scalings ----
        double aty = 0.0;
        #pragma unroll 4
        for (int j = 0; j < MEQ; ++j) aty += Ald[j * SA + tid] * readlane_f64(y_r, j);
        const double rd = p_i + aty - z_r;          // Q=0, G^T z = -z
        const double rs = s_r - x_r - u_i;          // -x + s - u
        const double mu = wave_sum_f64(s_r * z_r) * (1.0 / 64.0);
        const double rc = (SIGMA_C * mu - z_r * s_r + z_r * rs) / s_r;
        const double rx = rc - rd;                  // rhs_x
        const double d_r = s_r / z_r;
        const double v_r = d_r * rx + x_r;          // fy = A v - b

        double fy_r = 0.0;
        #pragma unroll 4
        for (int i = 0; i < NXV; ++i) fy_r += Ald[row * SA + i] * readlane_f64(v_r, i);
        fy_r -= b_r;

        dl[tid] = d_r;
        __syncthreads();                            // barrier 0: dl visible

        // ---- P2: S = A diag(d) A^T, 4x4 lower tiles (lanes<55) -> LDS ----
        if (tid < 55) {
            int uu = tid, mb = 0;
            while (uu > mb) { uu -= (mb + 1); ++mb; }
            const int nb = uu;
            double a00=0,a01=0,a02=0,a03=0, a10=0,a11=0,a12=0,a13=0,
                   a20=0,a21=0,a22=0,a23=0, a30=0,a31=0,a32=0,a33=0;
            const double* Am = &Ald[(4 * mb) * SA];
            const double* An = &Ald[(4 * nb) * SA];
            for (int k = 0; k < NXV; ++k) {
                const double dk = dl[k];
                const double r0 = Am[0*SA+k], r1 = Am[1*SA+k], r2 = Am[2*SA+k], r3 = Am[3*SA+k];
                const double c0 = An[0*SA+k]*dk, c1 = An[1*SA+k]*dk, c2 = An[2*SA+k]*dk, c3 = An[3*SA+k]*dk;
                a00 += r0*c0; a01 += r0*c1; a02 += r0*c2; a03 += r0*c3;
                a10 += r1*c0; a11 += r1*c1; a12 += r1*c2; a13 += r1*c3;
                a20 += r2*c0; a21 += r2*c1; a22 += r2*c2; a23 += r2*c3;
                a30 += r3*c0; a31 += r3*c1; a32 += r3*c2; a33 += r3*c3;
            }
            double* Sp = &Sl[(4 * mb) * SS + 4 * nb];
            Sp[0*SS+0]=a00; Sp[0*SS+1]=a01; Sp[0*SS+2]=a02; Sp[0*SS+3]=a03;
            Sp[1*SS+0]=a10; Sp[1*SS+1]=a11; Sp[1*SS+2]=a12; Sp[1*SS+3]=a13;
            Sp[2*SS+0]=a20; Sp[2*SS+1]=a21; Sp[2*SS+2]=a22; Sp[2*SS+3]=a23;
            Sp[3*SS+0]=a30; Sp[3*SS+1]=a31; Sp[3*SS+2]=a32; Sp[3*SS+3]=a33;
        }
        __syncthreads();   // barrier 1: tiles visible

        // ---- load row tid of S into registers (symmetric fill) ----
        double Sreg[MEQ];
        double diag_r;
        if (tid < MEQ) {
            #pragma unroll
            for (int j = 0; j < MEQ; ++j)
                Sreg[j] = (j <= tid) ? Sl[tid * SS + j] : Sl[j * SS + tid];
            diag_r = Sl[tid * SS + tid];
        } else {
            #pragma unroll
            for (int j = 0; j < MEQ; ++j) Sreg[j] = 0.0;
            diag_r = -1.0e308;
        }
        const double dg  = wave_max_f64(diag_r);
        const double thr = dg * PIV_DROP_REL;
        __syncthreads();   // barrier 2: Sl dead -> reuse as Lm store

        // ---- P3: greedy-max-pivot LDL^T; DPP argmax + readlane broadcasts ----
        double ip_own = 0.0;
        int    kk_own = 0;
        for (int t = 0; t < MEQ; ++t) {
            // packed-key argmax: sign-fixed hi32 of f64 | lane, DPP u32 max
            DU dd; dd.d = diag_r;
            const unsigned h  = dd.u[1];
            const unsigned mk = (h & 0x80000000u) ? ~h : (h | 0x80000000u);
            const unsigned key = wave_max_u32((mk & 0xFFFFFFC0u) | (unsigned)tid);
            const int kt = (int)(key & 63u);
            // col_i = S[i][kt] — 4 independent depth-10 chains + 3 combines
            double c0 = Sreg[0], c1 = Sreg[10], c2 = Sreg[20], c3 = Sreg[30];
            #pragma unroll
            for (int q = 1; q < 10; ++q) {
                if (kt == q)      c0 = Sreg[q];
                if (kt == 10 + q) c1 = Sreg[10 + q];
                if (kt == 20 + q) c2 = Sreg[20 + q];
                if (kt == 30 + q) c3 = Sreg[30 + q];
            }
            const double cl  = (kt < 10) ? c0 : c1;
            const double ch  = (kt < 30) ? c2 : c3;
            const double col = (kt < 20) ? cl : ch;

            const double piv  = readlane_f64(col, kt);
            double invP = 1.0 / piv;
            invP = (piv > thr) ? invP : 0.0;        // drop noise pivots
            if (tid == t) { kk_own = kt; ip_own = invP; }
            const double Lm = (diag_r > -1.0e307 && tid != kt) ? col * invP : 0.0;
            if (tid < MEQ) Sl[t * MEQ + tid] = Lm;  // multiplier -> dead LDS
            const double fyk = readlane_f64(fy_r, kt);
            fy_r -= Lm * fyk;                       // unit-L forward solve
            #pragma unroll
            for (int j = 0; j < MEQ; ++j)           // rank-1 trailing update
                Sreg[j] -= Lm * readlane_f64(Sreg[j], kt);
            diag_r -= Lm * col;                     // selector maintenance
            if (tid == kt) diag_r = -1.0e308;       // eliminated
        }

        // ---- P4: backward solve; Lm prefetched into dead Sreg registers ----
        #pragma unroll
        for (int t = 0; t < MEQ; ++t)
            Sreg[t] = (tid < MEQ) ? Sl[t * MEQ + tid] : 0.0;
        double X_r = 0.0;
        for (int t = MEQ - 1; t >= 0; --t) {
            double lx = 0.0;
            #pragma unroll
            for (int q = 0; q < MEQ; ++q) if (q == t) lx = Sreg[q];
            const double ssum = wave_sum_f64(lx * X_r);
            const int    kt2  = __builtin_amdgcn_readlane(kk_own, t);
            const double ipt  = readlane_f64(ip_own, t);
            const double fyk  = readlane_f64(fy_r, kt2);
            double xt = fyk * ipt - ssum;
            xt = (ipt != 0.0) ? xt : 0.0;           // dropped direction -> 0
            X_r = (tid == kt2) ? xt : X_r;
        }

        // ---- P5: dx/ds/dz, ratio test (DPP min), updates ----
        double atdy = 0.0;
        #pragma unroll 4
        for (int j = 0; j < MEQ; ++j) atdy += Ald[j * SA + tid] * readlane_f64(X_r, j);
        const double dx = d_r * (rx - atdy);
        const double ds = dx - rs;                   // -rs + dx
        const double dz = rc - (z_r / s_r) * dx;
        double r = 1.0e300;
        if (ds < 0.0) r = -s_r / ds;
        if (dz < 0.0) r = fmin(r, -z_r / dz);
        r = wave_min_f64(r);
        const double alpha = fmin(1.0, FTB_C * r);
        x_r += alpha * dx;
        s_r += alpha * ds;
        z_r += alpha * dz;
        y_r += alpha * X_r;                          // X_r==0 for lanes>=40
        __syncthreads();                             // Sl(Lm) dead before next P2
    }

    out[b * NXV + tid] = (float)x_r;
}

extern "C" void kernel_launch(void* const* d_in, const int* in_sizes, int n_in,
                              void* d_out, int out_size, void* d_ws, size_t ws_size,
                              hipStream_t stream) {
    const float* puzzles = (const float*)d_in[0];
    const float* A       = (const float*)d_in[1];   // declared f64, delivered f32
    const float* logz0   = (const float*)d_in[2];
    // d_in[3] = Q (zeros, structural), d_in[4] = G (-I, structural)
    const float* u       = (const float*)d_in[5];
    float* out = (float*)d_out;

    const int n_batch = in_sizes[0] / NXV;   // 1024
    qp_ipm_kernel<<<n_batch, 64, 0, stream>>>(puzzles, A, logz0, u, out);
}

// Round 18
// 1242.997 us; speedup vs baseline: 4.2830x; 1.4569x over previous
//
#include <hip/hip_runtime.h>
#include <math.h>

// QPLayer: batched primal-dual IPM, Q=0, G=-I (LP). f64 inputs DELIVERED AS F32
// (established round 8). Schur complement S = A diag(s/z) A^T (40x40), solved
// with COMPLETE-DIAGONAL-PIVOTED LDL^T (greedy max pivot; load-bearing), lane i
// owns row i of S in registers.
// ROUND 18: replace cross-lane broadcast machinery with a one-row LDS stage.
// Per step, lane kt writes its row (== pivot column, by symmetry) to Srow[40];
// then col_i = Srow[tid] (1 conflict-free read, replaces the 4x10 select
// chain) and the rank-1 update reads Srow[j] at UNIFORM addresses (LDS
// broadcast, overlaps FMA on VALU pipe) instead of 3200 v_readlane/iter.
// Pivot = readlane(diag_r, kt) (r11==r12 showed diag_r tracks stored copy).
// P4 t-loop unrolled (static Sreg[t]). Matvec broadcasts (y, v, X) staged
// through tiny LDS buffers -> uniform reads. |Lm|<=1 (greedy max) unchanged.
// 3 barriers/iter. One wave per batch element; 1024 waves = 4/CU (structural).
// LDS 35.9 KB -> 4 blocks/CU.

#define NXV   64
#define MEQ   40
#define NITER 25
#define SIGMA_C 0.1
#define FTB_C   0.99
#define SA 65    // LDS row stride for A (doubles)
#define SS 41    // LDS row stride for S staging (doubles); Sl reused for Lm
#define PIV_DROP_REL 1e-12

union DU { double d; int i[2]; unsigned u[2]; };

__device__ __forceinline__ double readlane_f64(double v, int lane) {
    DU a; a.d = v; DU r;
    r.i[0] = __builtin_amdgcn_readlane(a.i[0], lane);
    r.i[1] = __builtin_amdgcn_readlane(a.i[1], lane);
    return r.d;
}

// DPP wave64 reduction ladders (verified bit-exact rounds 16/17).
template<int CTRL>
__device__ __forceinline__ double dpp_add_step(double v) {
    DU a; a.d = v; DU b;
    b.i[0] = __builtin_amdgcn_update_dpp(0, a.i[0], CTRL, 0xf, 0xf, true);
    b.i[1] = __builtin_amdgcn_update_dpp(0, a.i[1], CTRL, 0xf, 0xf, true);
    return v + b.d;
}
__device__ __forceinline__ double wave_sum_f64(double v) {
    v = dpp_add_step<0x111>(v); v = dpp_add_step<0x112>(v);
    v = dpp_add_step<0x114>(v); v = dpp_add_step<0x118>(v);
    v = dpp_add_step<0x142>(v); v = dpp_add_step<0x143>(v);
    return readlane_f64(v, 63);
}
template<int CTRL>
__device__ __forceinline__ double dpp_min_step(double v) {   // identity +inf
    DU a; a.d = v; DU b;
    b.i[0] = __builtin_amdgcn_update_dpp(0x00000000, a.i[0], CTRL, 0xf, 0xf, false);
    b.i[1] = __builtin_amdgcn_update_dpp(0x7ff00000, a.i[1], CTRL, 0xf, 0xf, false);
    return fmin(v, b.d);
}
__device__ __forceinline__ double wave_min_f64(double v) {
    v = dpp_min_step<0x111>(v); v = dpp_min_step<0x112>(v);
    v = dpp_min_step<0x114>(v); v = dpp_min_step<0x118>(v);
    v = dpp_min_step<0x142>(v); v = dpp_min_step<0x143>(v);
    return readlane_f64(v, 63);
}
template<int CTRL>
__device__ __forceinline__ double dpp_max_step(double v) {   // identity -inf
    DU a; a.d = v; DU b;
    b.i[0] = __builtin_amdgcn_update_dpp(0x00000000, a.i[0], CTRL, 0xf, 0xf, false);
    b.i[1] = __builtin_amdgcn_update_dpp((int)0xfff00000u, a.i[1], CTRL, 0xf, 0xf, false);
    return fmax(v, b.d);
}
__device__ __forceinline__ double wave_max_f64(double v) {
    v = dpp_max_step<0x111>(v); v = dpp_max_step<0x112>(v);
    v = dpp_max_step<0x114>(v); v = dpp_max_step<0x118>(v);
    v = dpp_max_step<0x142>(v); v = dpp_max_step<0x143>(v);
    return readlane_f64(v, 63);
}
template<int CTRL>
__device__ __forceinline__ unsigned dpp_maxu_step(unsigned v) {
    unsigned m = (unsigned)__builtin_amdgcn_update_dpp(0, (int)v, CTRL, 0xf, 0xf, true);
    return v > m ? v : m;
}
__device__ __forceinline__ unsigned wave_max_u32(unsigned v) {
    v = dpp_maxu_step<0x111>(v); v = dpp_maxu_step<0x112>(v);
    v = dpp_maxu_step<0x114>(v); v = dpp_maxu_step<0x118>(v);
    v = dpp_maxu_step<0x142>(v); v = dpp_maxu_step<0x143>(v);
    return (unsigned)__builtin_amdgcn_readlane((int)v, 63);
}

__global__ __launch_bounds__(64, 1)
void qp_ipm_kernel(const float* __restrict__ puzzles,
                   const float* __restrict__ Af,
                   const float* __restrict__ lzf,
                   const float* __restrict__ uf,
                   float* __restrict__ out)
{
    __shared__ double Ald[MEQ * SA];   // 20,800 B
    __shared__ double Sl[MEQ * SS];    // 13,120 B (S staging, then Lm store)
    __shared__ double dl[NXV];         //    512 B (ez at setup, then d each iter)
    __shared__ double vl[NXV];         //    512 B (v staging for fy matvec)
    __shared__ double Srow[MEQ];       //    320 B (pivot-row stage)
    __shared__ double yl[MEQ];         //    320 B (y staging for aty matvec)
    __shared__ double Xl[MEQ];         //    320 B (dy staging for atdy matvec)

    const int tid = threadIdx.x;       // 0..63, one wave
    const int b   = blockIdx.x;
    const int row = (tid < MEQ) ? tid : 0;

    for (int e = tid; e < MEQ * NXV; e += 64)
        Ald[(e >> 6) * SA + (e & 63)] = (double)Af[e];
    dl[tid] = exp((double)lzf[tid]);
    if (tid < MEQ) yl[tid] = 0.0;
    __syncthreads();
    double b_r = 0.0;
    #pragma unroll 4
    for (int i = 0; i < NXV; ++i) b_r += Ald[row * SA + i] * dl[i];

    const double u_i = (double)uf[tid];
    const double p_i = -(double)puzzles[b * NXV + tid];
    double x_r = 0.0, s_r = 1.0, z_r = 1.0, y_r = 0.0;

    for (int it = 0; it < NITER; ++it) {
        // ---- P1: residuals/scalings; broadcasts via uniform LDS reads ----
        double aty = 0.0;
        #pragma unroll 4
        for (int j = 0; j < MEQ; ++j) aty += Ald[j * SA + tid] * yl[j];
        const double rd = p_i + aty - z_r;          // Q=0, G^T z = -z
        const double rs = s_r - x_r - u_i;          // -x + s - u
        const double mu = wave_sum_f64(s_r * z_r) * (1.0 / 64.0);
        const double rc = (SIGMA_C * mu - z_r * s_r + z_r * rs) / s_r;
        const double rx = rc - rd;                  // rhs_x
        const double d_r = s_r / z_r;
        const double v_r = d_r * rx + x_r;          // fy = A v - b
        vl[tid] = v_r;                              // same-wave order: write->read ok
        dl[tid] = d_r;

        double fy_r = 0.0;
        #pragma unroll 4
        for (int i = 0; i < NXV; ++i) fy_r += Ald[row * SA + i] * vl[i];
        fy_r -= b_r;
        __syncthreads();                            // barrier 0: dl visible

        // ---- P2: S = A diag(d) A^T, 4x4 lower tiles (lanes<55) -> LDS ----
        if (tid < 55) {
            int uu = tid, mb = 0;
            while (uu > mb) { uu -= (mb + 1); ++mb; }
            const int nb = uu;
            double a00=0,a01=0,a02=0,a03=0, a10=0,a11=0,a12=0,a13=0,
                   a20=0,a21=0,a22=0,a23=0, a30=0,a31=0,a32=0,a33=0;
            const double* Am = &Ald[(4 * mb) * SA];
            const double* An = &Ald[(4 * nb) * SA];
            for (int k = 0; k < NXV; ++k) {
                const double dk = dl[k];
                const double r0 = Am[0*SA+k], r1 = Am[1*SA+k], r2 = Am[2*SA+k], r3 = Am[3*SA+k];
                const double c0 = An[0*SA+k]*dk, c1 = An[1*SA+k]*dk, c2 = An[2*SA+k]*dk, c3 = An[3*SA+k]*dk;
                a00 += r0*c0; a01 += r0*c1; a02 += r0*c2; a03 += r0*c3;
                a10 += r1*c0; a11 += r1*c1; a12 += r1*c2; a13 += r1*c3;
                a20 += r2*c0; a21 += r2*c1; a22 += r2*c2; a23 += r2*c3;
                a30 += r3*c0; a31 += r3*c1; a32 += r3*c2; a33 += r3*c3;
            }
            double* Sp = &Sl[(4 * mb) * SS + 4 * nb];
            Sp[0*SS+0]=a00; Sp[0*SS+1]=a01; Sp[0*SS+2]=a02; Sp[0*SS+3]=a03;
            Sp[1*SS+0]=a10; Sp[1*SS+1]=a11; Sp[1*SS+2]=a12; Sp[1*SS+3]=a13;
            Sp[2*SS+0]=a20; Sp[2*SS+1]=a21; Sp[2*SS+2]=a22; Sp[2*SS+3]=a23;
            Sp[3*SS+0]=a30; Sp[3*SS+1]=a31; Sp[3*SS+2]=a32; Sp[3*SS+3]=a33;
        }
        __syncthreads();   // barrier 1: tiles visible

        // ---- load row tid of S into registers (symmetric fill) ----
        double Sreg[MEQ];
        double diag_r;
        if (tid < MEQ) {
            #pragma unroll
            for (int j = 0; j < MEQ; ++j)
                Sreg[j] = (j <= tid) ? Sl[tid * SS + j] : Sl[j * SS + tid];
            diag_r = Sl[tid * SS + tid];
        } else {
            #pragma unroll
            for (int j = 0; j < MEQ; ++j) Sreg[j] = 0.0;
            diag_r = -1.0e308;
        }
        const double dg  = wave_max_f64(diag_r);
        const double thr = dg * PIV_DROP_REL;
        __syncthreads();   // barrier 2: Sl dead -> reuse as Lm store

        // ---- P3: greedy-max-pivot LDL^T; pivot row staged through Srow ----
        double ip_own = 0.0;
        int    kk_own = 0;
        for (int t = 0; t < MEQ; ++t) {
            // packed-key argmax: sign-fixed hi32 of f64 | lane, DPP u32 max
            DU dd; dd.d = diag_r;
            const unsigned h  = dd.u[1];
            const unsigned mk = (h & 0x80000000u) ? ~h : (h | 0x80000000u);
            const unsigned key = wave_max_u32((mk & 0xFFFFFFC0u) | (unsigned)tid);
            const int kt = (int)(key & 63u);
            const double piv  = readlane_f64(diag_r, kt);   // == stored diag
            double invP = 1.0 / piv;
            invP = (piv > thr) ? invP : 0.0;        // drop noise pivots
            if (tid == t) { kk_own = kt; ip_own = invP; }
            // stage pivot row (lane kt; its row is frozen this step)
            if (tid == kt) {
                #pragma unroll
                for (int j = 0; j < MEQ; ++j) Srow[j] = Sreg[j];
            }
            const double col = Srow[row];           // S[kt][i] == S[i][kt] (symmetry)
            const double Lm  = (diag_r > -1.0e307 && tid != kt) ? col * invP : 0.0;
            if (tid < MEQ) Sl[t * MEQ + tid] = Lm;  // multiplier -> dead LDS
            const double fyk = readlane_f64(fy_r, kt);
            fy_r -= Lm * fyk;                       // unit-L forward solve
            #pragma unroll
            for (int j = 0; j < MEQ; ++j)           // rank-1: uniform broadcast reads
                Sreg[j] -= Lm * Srow[j];
            diag_r -= Lm * col;                     // selector maintenance
            if (tid == kt) diag_r = -1.0e308;       // eliminated
        }

        // ---- P4: backward solve; Lm prefetched into dead Sreg, static t ----
        #pragma unroll
        for (int t = 0; t < MEQ; ++t)
            Sreg[t] = (tid < MEQ) ? Sl[t * MEQ + tid] : 0.0;
        double X_r = 0.0;
        #pragma unroll
        for (int t = MEQ - 1; t >= 0; --t) {
            const double ssum = wave_sum_f64(Sreg[t] * X_r);
            const int    kt2  = __builtin_amdgcn_readlane(kk_own, t);
            const double ipt  = readlane_f64(ip_own, t);
            const double fyk  = readlane_f64(fy_r, kt2);
            double xt = fyk * ipt - ssum;
            xt = (ipt != 0.0) ? xt : 0.0;           // dropped direction -> 0
            X_r = (tid == kt2) ? xt : X_r;
        }
        if (tid < MEQ) Xl[tid] = X_r;               // stage dy for atdy matvec

        // ---- P5: dx/ds/dz, ratio test (DPP min), updates ----
        double atdy = 0.0;
        #pragma unroll 4
        for (int j = 0; j < MEQ; ++j) atdy += Ald[j * SA + tid] * Xl[j];
        const double dx = d_r * (rx - atdy);
        const double ds = dx - rs;                   // -rs + dx
        const double dz = rc - (z_r / s_r) * dx;
        double r = 1.0e300;
        if (ds < 0.0) r = -s_r / ds;
        if (dz < 0.0) r = fmin(r, -z_r / dz);
        r = wave_min_f64(r);
        const double alpha = fmin(1.0, FTB_C * r);
        x_r += alpha * dx;
        s_r += alpha * ds;
        z_r += alpha * dz;
        y_r += alpha * X_r;                          // X_r==0 for lanes>=40
        if (tid < MEQ) yl[tid] = y_r;                // stage y for next aty
        __syncthreads();                             // Sl(Lm)/Xl/yl settle
    }

    out[b * NXV + tid] = (float)x_r;
}

extern "C" void kernel_launch(void* const* d_in, const int* in_sizes, int n_in,
                              void* d_out, int out_size, void* d_ws, size_t ws_size,
                              hipStream_t stream) {
    const float* puzzles = (const float*)d_in[0];
    const float* A       = (const float*)d_in[1];   // declared f64, delivered f32
    const float* logz0   = (const float*)d_in[2];
    // d_in[3] = Q (zeros, structural), d_in[4] = G (-I, structural)
    const float* u       = (const float*)d_in[5];
    float* out = (float*)d_out;

    const int n_batch = in_sizes[0] / NXV;   // 1024
    qp_ipm_kernel<<<n_batch, 64, 0, stream>>>(puzzles, A, logz0, u, out);
}